// Round 6
// baseline (615.550 us; speedup 1.0000x reference)
//
#include <hip/hip_runtime.h>

typedef unsigned int u32;

#define NS    8192
#define NQ    16384
#define DD    128
#define TOPK  32
#define RR    16
#define CAP   320
#define TAU   0.17f

// ---------- prep: numpy-exact norms + normalized transpose x_t[k][j] -------
__global__ __launch_bounds__(256) void prep_kernel(const float* __restrict__ s_emb,
                                                   float* __restrict__ x_t) {
    __shared__ float tile[64][129];
    __shared__ float nrm[64];
    const int row0 = blockIdx.x * 64;
    const int tid = threadIdx.x;
    for (int it = 0; it < 32; ++it) {
        int idx = it * 256 + tid;
        int rr = idx >> 7, cc = idx & 127;
        tile[rr][cc] = s_emb[(size_t)(row0 + rr) * DD + cc];
    }
    __syncthreads();
    if (tid < 64) {
        // numpy pairwise_sum(n=128): 8 accumulators stride-8, tree combine
        float r8[8];
#pragma unroll
        for (int c = 0; c < 8; ++c) { float v = tile[tid][c]; r8[c] = __fmul_rn(v, v); }
        for (int m = 1; m < 16; ++m) {
#pragma unroll
            for (int c = 0; c < 8; ++c) {
                float v = tile[tid][8 * m + c];
                r8[c] = __fadd_rn(r8[c], __fmul_rn(v, v));
            }
        }
        float res = __fadd_rn(
            __fadd_rn(__fadd_rn(r8[0], r8[1]), __fadd_rn(r8[2], r8[3])),
            __fadd_rn(__fadd_rn(r8[4], r8[5]), __fadd_rn(r8[6], r8[7])));
        nrm[tid] = __fsqrt_rn(res);
    }
    __syncthreads();
    const int lane = tid & 63, w = tid >> 6;
    for (int m = 0; m < 32; ++m) {
        int k = w * 32 + m;
        x_t[(size_t)k * NS + row0 + lane] = __fdiv_rn(tile[lane][k], nrm[lane]);
    }
}

// ---------- prototypes + K,V projections -> kv (512 floats) ----------------
__global__ __launch_bounds__(512) void protokv_kernel(
    const float* __restrict__ s_emb,
    const float* __restrict__ Wk, const float* __restrict__ bk,
    const float* __restrict__ Wv, const float* __restrict__ bv,
    float* __restrict__ kv) {
    __shared__ double ps[512];
    __shared__ double prd[DD];
    const int j = blockIdx.x;           // 0 = pos proto (second half), 1 = neg
    const int tid = threadIdx.x;
    const int sub = tid >> 7, d = tid & 127;
    const size_t row0 = (size_t)(j == 0 ? 4096 : 0) + (size_t)sub * 1024;
    double acc = 0.0;
    for (int r = 0; r < 1024; ++r)
        acc += (double)s_emb[(row0 + r) * DD + d];
    ps[tid] = acc;
    __syncthreads();
    if (sub == 0)
        prd[d] = (ps[d] + ps[128 + d] + ps[256 + d] + ps[384 + d]) * (1.0 / 4096.0);
    __syncthreads();
    if (tid < DD) {
        double ka = (double)bk[tid];
        double va = (double)bv[tid];
        for (int e = 0; e < DD; ++e) {
            double p = prd[e];
            ka += p * (double)Wk[tid * DD + e];
            va += p * (double)Wv[tid * DD + e];
        }
        kv[j * DD + tid]          = (float)ka;
        kv[2 * DD + j * DD + tid] = (float)va;
    }
}

// ---------- sim + top-32 + aggregate; ties at equal sim -> HIGHER index -----
__global__ __launch_bounds__(256) void sim_topk_kernel(
    const float* __restrict__ s_emb, const float* __restrict__ x_t,
    const float* __restrict__ alpha_p, float* __restrict__ out_s) {
    __shared__ float candv[RR][CAP];
    __shared__ int   candj[RR][CAP];
    __shared__ int   cnt[RR];
    __shared__ int   winners[RR][TOPK];
    __shared__ float redv[RR][16];
    __shared__ int   redj[RR][16];
    __shared__ int   redp[RR][16];

    const int i0 = blockIdx.x * RR;
    const int tid = threadIdx.x;
    if (tid < RR) cnt[tid] = 0;
    __syncthreads();

    // ---- sim pass: per (i,j), single sequential FMA chain over k (np order)
    for (int jt = 0; jt < 16; ++jt) {
        const int j0 = jt * 512 + tid;          // and j0 + 256
        float acc0[RR], acc1[RR];
#pragma unroll
        for (int r = 0; r < RR; ++r) { acc0[r] = 0.f; acc1[r] = 0.f; }
        for (int k = 0; k < 128; ++k) {
            const float* row = x_t + (size_t)k * NS;
            float xa = row[j0];
            float xb = row[j0 + 256];
            const float* xi = row + i0;          // wave-uniform -> s_load
#pragma unroll
            for (int r = 0; r < RR; ++r) {
                float w = xi[r];
                acc0[r] = fmaf(w, xa, acc0[r]);
                acc1[r] = fmaf(w, xb, acc1[r]);
            }
        }
#pragma unroll
        for (int r = 0; r < RR; ++r) {
            if (acc0[r] >= TAU) {
                int p = atomicAdd(&cnt[r], 1);
                if (p < CAP) { candv[r][p] = acc0[r]; candj[r][p] = j0; }
            }
            if (acc1[r] >= TAU) {
                int p = atomicAdd(&cnt[r], 1);
                if (p < CAP) { candv[r][p] = acc1[r]; candj[r][p] = j0 + 256; }
            }
        }
    }
    __syncthreads();

    // ---- top-32 per row among candidates (val desc, idx DESC on ties) -----
    const int r = tid >> 4, t = tid & 15;
    const int n = (cnt[r] < CAP) ? cnt[r] : CAP;
    for (int it = 0; it < TOPK; ++it) {
        float bv = -3.0e38f; int bj = -1, bp = -1;
        for (int p = t; p < n; p += 16) {
            float v = candv[r][p]; int j = candj[r][p];
            if (v > bv || (v == bv && j > bj)) { bv = v; bj = j; bp = p; }
        }
        redv[r][t] = bv; redj[r][t] = bj; redp[r][t] = bp;
        __syncthreads();
        if (t == 0) {
            float wv = -3.0e38f; int wj = -1, wp = -1;
            for (int q = 0; q < 16; ++q) {
                float v = redv[r][q]; int j = redj[r][q];
                if (v > wv || (v == wv && j > wj)) { wv = v; wj = j; wp = redp[r][q]; }
            }
            if ((u32)wj >= NS) wj = 0;               // safety clamp
            winners[r][it] = wj;
            if (wp >= 0) candv[r][wp] = -3.0e38f;    // remove from pool
        }
        __syncthreads();
    }

    // ---- sort winners ascending (index order = np aggregation order) ------
    if (t == 0) {
        for (int a = 1; a < TOPK; ++a) {
            int key = winners[r][a]; int b = a - 1;
            while (b >= 0 && winners[r][b] > key) { winners[r][b + 1] = winners[r][b]; --b; }
            winners[r][b + 1] = key;
        }
    }
    __syncthreads();

    // ---- aggregate + epilogue (value-level; order ascending) --------------
    const float alpha = alpha_p[0];
    const int d = tid & 127;
    for (int rp = 0; rp < 8; ++rp) {
        const int rw = rp * 2 + (tid >> 7);
        float a = 0.0f;
        for (int w = 0; w < TOPK; ++w)
            a = __fadd_rn(a, s_emb[(size_t)winners[rw][w] * DD + d]);
        float base = s_emb[(size_t)(i0 + rw) * DD + d];
        out_s[(size_t)(i0 + rw) * DD + d] = __fadd_rn(base, __fmul_rn(alpha, a));
    }
}

// ---------- queries rows [0, 16380): Q proj + 2-way attention --------------
__global__ __launch_bounds__(128) void query_kernel(
    const float* __restrict__ q_emb, const float* __restrict__ Wq,
    const float* __restrict__ bq, const float* __restrict__ kv,
    const float* __restrict__ alpha_p, float* __restrict__ out_q) {
    __shared__ float qv[DD];
    __shared__ float r0[DD], r1[DD];
    const int i = blockIdx.x, d = threadIdx.x;

    qv[d] = q_emb[(size_t)i * DD + d];
    __syncthreads();

    float acc = bq[d];
    const float4* wr = (const float4*)(Wq + (size_t)d * DD);
#pragma unroll
    for (int c = 0; c < 32; ++c) {
        float4 w = wr[c];
        const int e = c * 4;
        acc += qv[e + 0] * w.x;
        acc += qv[e + 1] * w.y;
        acc += qv[e + 2] * w.z;
        acc += qv[e + 3] * w.w;
    }
    r0[d] = acc * kv[d];
    r1[d] = acc * kv[DD + d];
    __syncthreads();
#pragma unroll
    for (int s = 64; s > 0; s >>= 1) {
        if (d < s) { r0[d] += r0[d + s]; r1[d] += r1[d + s]; }
        __syncthreads();
    }
    const float inv_scale = 0.088388347648318447f;   // 1/sqrt(128)
    float l0 = r0[0] * inv_scale;
    float l1 = r1[0] * inv_scale;
    float m = fmaxf(l0, l1);
    float e0 = expf(l0 - m), e1 = expf(l1 - m);
    float inv = 1.0f / (e0 + e1);
    float a0 = e0 * inv, a1 = e1 * inv;
    float ctx = a0 * kv[2 * DD + d] + a1 * kv[3 * DD + d];
    float alpha = alpha_p[0];
    out_q[(size_t)i * DD + d] = __fadd_rn(qv[d], __fmul_rn(alpha, ctx));
}

// ---------- last 4 query rows (their output slots host the kv scratch) -----
__global__ __launch_bounds__(128) void query_tail_kernel(
    const float* __restrict__ q_emb, const float* __restrict__ Wq,
    const float* __restrict__ bq, const float* __restrict__ kvg,
    const float* __restrict__ alpha_p, float* __restrict__ out_q) {
    __shared__ float kvl[512];
    __shared__ float qv[DD];
    __shared__ float r0[DD], r1[DD];
    const int d = threadIdx.x;
#pragma unroll
    for (int c = 0; c < 4; ++c) kvl[c * DD + d] = kvg[c * DD + d];
    __syncthreads();

    for (int rr = 0; rr < 4; ++rr) {
        const int i = NQ - 4 + rr;
        qv[d] = q_emb[(size_t)i * DD + d];
        __syncthreads();
        float acc = bq[d];
        const float4* wr = (const float4*)(Wq + (size_t)d * DD);
#pragma unroll
        for (int c = 0; c < 32; ++c) {
            float4 w = wr[c];
            const int e = c * 4;
            acc += qv[e + 0] * w.x;
            acc += qv[e + 1] * w.y;
            acc += qv[e + 2] * w.z;
            acc += qv[e + 3] * w.w;
        }
        r0[d] = acc * kvl[d];
        r1[d] = acc * kvl[DD + d];
        __syncthreads();
#pragma unroll
        for (int s = 64; s > 0; s >>= 1) {
            if (d < s) { r0[d] += r0[d + s]; r1[d] += r1[d + s]; }
            __syncthreads();
        }
        const float inv_scale = 0.088388347648318447f;
        float l0 = r0[0] * inv_scale;
        float l1 = r1[0] * inv_scale;
        float m = fmaxf(l0, l1);
        float e0 = expf(l0 - m), e1 = expf(l1 - m);
        float inv = 1.0f / (e0 + e1);
        float a0 = e0 * inv, a1 = e1 * inv;
        float ctx = a0 * kvl[2 * DD + d] + a1 * kvl[3 * DD + d];
        float alpha = alpha_p[0];
        float res = __fadd_rn(qv[d], __fmul_rn(alpha, ctx));
        __syncthreads();                 // everyone done reading kvl/qv
        out_q[(size_t)i * DD + d] = res; // overwrites kv scratch region last
        __syncthreads();
    }
}

extern "C" void kernel_launch(void* const* d_in, const int* in_sizes, int n_in,
                              void* d_out, int out_size, void* d_ws, size_t ws_size,
                              hipStream_t stream) {
    (void)in_sizes; (void)n_in; (void)d_ws; (void)ws_size; (void)out_size;
    const float* s_emb = (const float*)d_in[0];
    const float* q_emb = (const float*)d_in[1];
    const float* Wq = (const float*)d_in[2];
    const float* bq = (const float*)d_in[3];
    const float* Wk = (const float*)d_in[4];
    const float* bk = (const float*)d_in[5];
    const float* Wv = (const float*)d_in[6];
    const float* bv = (const float*)d_in[7];
    const float* alpha_msg  = (const float*)d_in[8];
    const float* alpha_attn = (const float*)d_in[9];
    float* out = (float*)d_out;

    float* out_q = out + (size_t)NS * DD;                 // query outputs
    float* x_t   = out_q;                                 // 4 MB scratch (out_q rows 0..8191)
    float* kv    = out + (size_t)(NS + NQ) * DD - 512;    // last 4 rows of out_q

    prep_kernel<<<NS / 64, 256, 0, stream>>>(s_emb, x_t);
    protokv_kernel<<<2, 512, 0, stream>>>(s_emb, Wk, bk, Wv, bv, kv);
    sim_topk_kernel<<<NS / RR, 256, 0, stream>>>(s_emb, x_t, alpha_msg, out);
    query_kernel<<<NQ - 4, 128, 0, stream>>>(q_emb, Wq, bq, kv, alpha_attn, out_q);
    query_tail_kernel<<<1, 128, 0, stream>>>(q_emb, Wq, bq, kv, alpha_attn, out_q);
}

// Round 7
// 509.193 us; speedup vs baseline: 1.2089x; 1.2089x over previous
//
#include <hip/hip_runtime.h>

typedef unsigned int u32;

#define NS    8192
#define NQ    16384
#define DD    128
#define TOPK  32
#define RR    16
#define CAP   320
#define TAU   0.17f

// ---------- prep: numpy-exact norms + normalized transpose x_t[k][j] -------
// (bit-identical to the passing R6 version — decision path depends on it)
__global__ __launch_bounds__(256) void prep_kernel(const float* __restrict__ s_emb,
                                                   float* __restrict__ x_t) {
    __shared__ float tile[64][129];
    __shared__ float nrm[64];
    const int row0 = blockIdx.x * 64;
    const int tid = threadIdx.x;
    for (int it = 0; it < 32; ++it) {
        int idx = it * 256 + tid;
        int rr = idx >> 7, cc = idx & 127;
        tile[rr][cc] = s_emb[(size_t)(row0 + rr) * DD + cc];
    }
    __syncthreads();
    if (tid < 64) {
        float r8[8];
#pragma unroll
        for (int c = 0; c < 8; ++c) { float v = tile[tid][c]; r8[c] = __fmul_rn(v, v); }
        for (int m = 1; m < 16; ++m) {
#pragma unroll
            for (int c = 0; c < 8; ++c) {
                float v = tile[tid][8 * m + c];
                r8[c] = __fadd_rn(r8[c], __fmul_rn(v, v));
            }
        }
        float res = __fadd_rn(
            __fadd_rn(__fadd_rn(r8[0], r8[1]), __fadd_rn(r8[2], r8[3])),
            __fadd_rn(__fadd_rn(r8[4], r8[5]), __fadd_rn(r8[6], r8[7])));
        nrm[tid] = __fsqrt_rn(res);
    }
    __syncthreads();
    const int lane = tid & 63, w = tid >> 6;
    for (int m = 0; m < 32; ++m) {
        int k = w * 32 + m;
        x_t[(size_t)k * NS + row0 + lane] = __fdiv_rn(tile[lane][k], nrm[lane]);
    }
}

// ---------- proto partial sums: 16 blocks x 512 rows ------------------------
__global__ __launch_bounds__(256) void proto_part_kernel(const float* __restrict__ s_emb,
                                                         double* __restrict__ part) {
    __shared__ double ps[256];
    const int b = blockIdx.x;              // 0..15 ; h = b>>3: 0=first half(neg),1=second(pos)
    const int h = b >> 3, seg = b & 7;
    const int tid = threadIdx.x;
    const int sub = tid >> 7, d = tid & 127;
    const size_t row0 = (size_t)h * 4096 + (size_t)seg * 512 + (size_t)sub * 256;
    double acc = 0.0;
    for (int r = 0; r < 256; ++r)
        acc += (double)s_emb[(row0 + r) * DD + d];
    ps[tid] = acc;
    __syncthreads();
    if (sub == 0) part[(size_t)b * DD + d] = ps[d] + ps[128 + d];
}

// ---------- combine partials -> prototypes -> K,V (kv = 512 floats) --------
__global__ __launch_bounds__(256) void kv_kernel(
    const double* __restrict__ part,
    const float* __restrict__ Wk, const float* __restrict__ bk,
    const float* __restrict__ Wv, const float* __restrict__ bv,
    float* __restrict__ kv) {
    __shared__ double prd[2][DD];
    const int tid = threadIdx.x;
    const int j = tid >> 7, d = tid & 127;   // j: 0=pos(second half), 1=neg(first half)
    {
        const int h = (j == 0) ? 1 : 0;
        double s = 0.0;
        for (int b = 0; b < 8; ++b) s += part[(size_t)(h * 8 + b) * DD + d];
        prd[j][d] = s * (1.0 / 4096.0);
    }
    __syncthreads();
    double ka = (double)bk[d], va = (double)bv[d];
    for (int e = 0; e < DD; ++e) {
        double p = prd[j][e];
        ka += p * (double)Wk[d * DD + e];
        va += p * (double)Wv[d * DD + e];
    }
    kv[j * DD + d]          = (float)ka;
    kv[2 * DD + j * DD + d] = (float)va;
}

// ---------- sim + top-32 + aggregate; exact chain, ties -> HIGHER index ----
__global__ __launch_bounds__(256) void sim_topk_kernel(
    const float* __restrict__ s_emb, const float* __restrict__ x_t,
    const float* __restrict__ alpha_p, float* __restrict__ out_s) {
    __shared__ float ti[DD][RR];          // i-tile, k-major (8 KB)
    __shared__ float candv[RR][CAP];
    __shared__ int   candj[RR][CAP];
    __shared__ int   cnt[RR];
    __shared__ int   winners[RR][TOPK];
    __shared__ float redv[RR][16];
    __shared__ int   redj[RR][16];
    __shared__ int   redp[RR][16];

    const int i0 = blockIdx.x * RR;
    const int tid = threadIdx.x;
    if (tid < RR) cnt[tid] = 0;
    for (int u = tid; u < DD * RR; u += 256) {
        int k = u >> 4, r = u & 15;
        ti[k][r] = x_t[(size_t)k * NS + i0 + r];
    }
    __syncthreads();

    // ---- sim pass: per (i,j) a single sequential FMA chain over k ascending
    for (int jt = 0; jt < 8; ++jt) {
        const int jb = jt * 1024 + tid;   // j = jb + 256*c, c=0..3
        float acc[RR][4];
#pragma unroll
        for (int r = 0; r < RR; ++r) {
            acc[r][0] = 0.f; acc[r][1] = 0.f; acc[r][2] = 0.f; acc[r][3] = 0.f;
        }
        for (int k = 0; k < DD; ++k) {
            const float* row = x_t + (size_t)k * NS + jb;
            float x0 = row[0];
            float x1 = row[256];
            float x2 = row[512];
            float x3 = row[768];
#pragma unroll
            for (int r = 0; r < RR; ++r) {
                float w = ti[k][r];
                acc[r][0] = fmaf(w, x0, acc[r][0]);
                acc[r][1] = fmaf(w, x1, acc[r][1]);
                acc[r][2] = fmaf(w, x2, acc[r][2]);
                acc[r][3] = fmaf(w, x3, acc[r][3]);
            }
        }
#pragma unroll
        for (int r = 0; r < RR; ++r) {
#pragma unroll
            for (int c = 0; c < 4; ++c) {
                if (acc[r][c] >= TAU) {
                    int p = atomicAdd(&cnt[r], 1);
                    if (p < CAP) { candv[r][p] = acc[r][c]; candj[r][p] = jb + c * 256; }
                }
            }
        }
    }
    __syncthreads();

    // ---- top-32 per row among candidates (val desc, idx DESC on ties) -----
    const int r = tid >> 4, t = tid & 15;
    const int n = (cnt[r] < CAP) ? cnt[r] : CAP;
    for (int it = 0; it < TOPK; ++it) {
        float bv = -3.0e38f; int bj = -1, bp = -1;
        for (int p = t; p < n; p += 16) {
            float v = candv[r][p]; int j = candj[r][p];
            if (v > bv || (v == bv && j > bj)) { bv = v; bj = j; bp = p; }
        }
        redv[r][t] = bv; redj[r][t] = bj; redp[r][t] = bp;
        __syncthreads();
        if (t == 0) {
            float wv = -3.0e38f; int wj = -1, wp = -1;
            for (int q = 0; q < 16; ++q) {
                float v = redv[r][q]; int j = redj[r][q];
                if (v > wv || (v == wv && j > wj)) { wv = v; wj = j; wp = redp[r][q]; }
            }
            if ((u32)wj >= NS) wj = 0;               // safety clamp
            winners[r][it] = wj;
            if (wp >= 0) candv[r][wp] = -3.0e38f;
        }
        __syncthreads();
    }

    // ---- sort winners ascending --------------------------------------------
    if (t == 0) {
        for (int a = 1; a < TOPK; ++a) {
            int key = winners[r][a]; int b = a - 1;
            while (b >= 0 && winners[r][b] > key) { winners[r][b + 1] = winners[r][b]; --b; }
            winners[r][b + 1] = key;
        }
    }
    __syncthreads();

    // ---- aggregate + epilogue ----------------------------------------------
    const float alpha = alpha_p[0];
    const int d = tid & 127;
    for (int rp = 0; rp < 8; ++rp) {
        const int rw = rp * 2 + (tid >> 7);
        float a = 0.0f;
        for (int w = 0; w < TOPK; ++w)
            a = __fadd_rn(a, s_emb[(size_t)winners[rw][w] * DD + d]);
        float base = s_emb[(size_t)(i0 + rw) * DD + d];
        out_s[(size_t)(i0 + rw) * DD + d] = __fadd_rn(base, __fmul_rn(alpha, a));
    }
}

// ---------- queries: LDS-tiled GEMM (64 rows/block) + 2-way attention ------
__global__ __launch_bounds__(256) void query_kernel(
    const float* __restrict__ q_emb, const float* __restrict__ Wq,
    const float* __restrict__ bq, const float* __restrict__ kv,
    const float* __restrict__ alpha_p, float* __restrict__ out_q) {
    __shared__ float wqT[DD][132];    // [e][d]
    __shared__ float qtT[DD][68];     // [e][i]
    __shared__ float qo[64][129];     // Q outputs [i][d]
    __shared__ float a0s[64], a1s[64];
    const int row0 = blockIdx.x * 64;
    const int tid = threadIdx.x;

    for (int u = tid; u < DD * DD; u += 256) {
        int dd = u >> 7, ee = u & 127;
        wqT[ee][dd] = Wq[u];
    }
    for (int u = tid; u < 64 * DD; u += 256) {
        int ii = u >> 7, ee = u & 127;
        qtT[ee][ii] = q_emb[(size_t)row0 * DD + u];
    }
    __syncthreads();

    const int d0 = (tid & 31) * 4, i0 = (tid >> 5) * 8;
    float acc[8][4];
    {
        float b0 = bq[d0], b1 = bq[d0 + 1], b2 = bq[d0 + 2], b3 = bq[d0 + 3];
#pragma unroll
        for (int ii = 0; ii < 8; ++ii) {
            acc[ii][0] = b0; acc[ii][1] = b1; acc[ii][2] = b2; acc[ii][3] = b3;
        }
    }
    for (int e = 0; e < DD; ++e) {
        float4 wv = *(const float4*)&wqT[e][d0];
        float4 qa = *(const float4*)&qtT[e][i0];
        float4 qb = *(const float4*)&qtT[e][i0 + 4];
        float qs[8] = {qa.x, qa.y, qa.z, qa.w, qb.x, qb.y, qb.z, qb.w};
#pragma unroll
        for (int ii = 0; ii < 8; ++ii) {
            acc[ii][0] = fmaf(qs[ii], wv.x, acc[ii][0]);
            acc[ii][1] = fmaf(qs[ii], wv.y, acc[ii][1]);
            acc[ii][2] = fmaf(qs[ii], wv.z, acc[ii][2]);
            acc[ii][3] = fmaf(qs[ii], wv.w, acc[ii][3]);
        }
    }
#pragma unroll
    for (int ii = 0; ii < 8; ++ii) {
        qo[i0 + ii][d0 + 0] = acc[ii][0];
        qo[i0 + ii][d0 + 1] = acc[ii][1];
        qo[i0 + ii][d0 + 2] = acc[ii][2];
        qo[i0 + ii][d0 + 3] = acc[ii][3];
    }
    __syncthreads();
    if (tid < 64) {
        float l0 = 0.f, l1 = 0.f;
        for (int e = 0; e < DD; ++e) {
            float q = qo[tid][e];
            l0 = fmaf(q, kv[e], l0);
            l1 = fmaf(q, kv[DD + e], l1);
        }
        const float inv_scale = 0.088388347648318447f;   // 1/sqrt(128)
        l0 *= inv_scale; l1 *= inv_scale;
        float m = fmaxf(l0, l1);
        float e0 = expf(l0 - m), e1 = expf(l1 - m);
        float inv = 1.0f / (e0 + e1);
        a0s[tid] = e0 * inv; a1s[tid] = e1 * inv;
    }
    __syncthreads();
    const float alpha = alpha_p[0];
    for (int w = 0; w < 32; ++w) {
        int idx = w * 256 + tid;
        int ii = idx >> 7, dd = idx & 127;
        int gi = row0 + ii;
        if (gi < NQ - 4) {
            float ctx = a0s[ii] * kv[2 * DD + dd] + a1s[ii] * kv[3 * DD + dd];
            out_q[(size_t)gi * DD + dd] =
                __fadd_rn(q_emb[(size_t)gi * DD + dd], __fmul_rn(alpha, ctx));
        }
    }
}

// ---------- last 4 query rows (their output slots host the kv scratch) -----
__global__ __launch_bounds__(128) void query_tail_kernel(
    const float* __restrict__ q_emb, const float* __restrict__ Wq,
    const float* __restrict__ bq, const float* __restrict__ kvg,
    const float* __restrict__ alpha_p, float* __restrict__ out_q) {
    __shared__ float kvl[512];
    __shared__ float qv[DD];
    __shared__ float r0[DD], r1[DD];
    const int d = threadIdx.x;
#pragma unroll
    for (int c = 0; c < 4; ++c) kvl[c * DD + d] = kvg[c * DD + d];
    __syncthreads();

    for (int rr = 0; rr < 4; ++rr) {
        const int i = NQ - 4 + rr;
        qv[d] = q_emb[(size_t)i * DD + d];
        __syncthreads();
        float acc = bq[d];
        const float4* wr = (const float4*)(Wq + (size_t)d * DD);
#pragma unroll
        for (int c = 0; c < 32; ++c) {
            float4 w = wr[c];
            const int e = c * 4;
            acc += qv[e + 0] * w.x;
            acc += qv[e + 1] * w.y;
            acc += qv[e + 2] * w.z;
            acc += qv[e + 3] * w.w;
        }
        r0[d] = acc * kvl[d];
        r1[d] = acc * kvl[DD + d];
        __syncthreads();
#pragma unroll
        for (int s = 64; s > 0; s >>= 1) {
            if (d < s) { r0[d] += r0[d + s]; r1[d] += r1[d + s]; }
            __syncthreads();
        }
        const float inv_scale = 0.088388347648318447f;
        float l0 = r0[0] * inv_scale;
        float l1 = r1[0] * inv_scale;
        float m = fmaxf(l0, l1);
        float e0 = expf(l0 - m), e1 = expf(l1 - m);
        float inv = 1.0f / (e0 + e1);
        float a0 = e0 * inv, a1 = e1 * inv;
        float ctx = a0 * kvl[2 * DD + d] + a1 * kvl[3 * DD + d];
        float alpha = alpha_p[0];
        float res = __fadd_rn(qv[d], __fmul_rn(alpha, ctx));
        __syncthreads();
        out_q[(size_t)i * DD + d] = res;
        __syncthreads();
    }
}

extern "C" void kernel_launch(void* const* d_in, const int* in_sizes, int n_in,
                              void* d_out, int out_size, void* d_ws, size_t ws_size,
                              hipStream_t stream) {
    (void)in_sizes; (void)n_in; (void)d_ws; (void)ws_size; (void)out_size;
    const float* s_emb = (const float*)d_in[0];
    const float* q_emb = (const float*)d_in[1];
    const float* Wq = (const float*)d_in[2];
    const float* bq = (const float*)d_in[3];
    const float* Wk = (const float*)d_in[4];
    const float* bk = (const float*)d_in[5];
    const float* Wv = (const float*)d_in[6];
    const float* bv = (const float*)d_in[7];
    const float* alpha_msg  = (const float*)d_in[8];
    const float* alpha_attn = (const float*)d_in[9];
    float* out = (float*)d_out;

    float*  out_q = out + (size_t)NS * DD;                  // query outputs
    float*  x_t   = out_q;                                  // 4 MB scratch (out_q rows 0..8191)
    double* part  = (double*)(out_q + (size_t)NS * DD);     // 16 KB (out_q rows 8192..8223)
    float*  kv    = out + (size_t)(NS + NQ) * DD - 512;     // last 4 rows of out_q

    prep_kernel<<<NS / 64, 256, 0, stream>>>(s_emb, x_t);
    proto_part_kernel<<<16, 256, 0, stream>>>(s_emb, part);
    kv_kernel<<<1, 256, 0, stream>>>(part, Wk, bk, Wv, bv, kv);
    sim_topk_kernel<<<NS / RR, 256, 0, stream>>>(s_emb, x_t, alpha_msg, out);
    query_kernel<<<NQ / 64, 256, 0, stream>>>(q_emb, Wq, bq, kv, alpha_attn, out_q);
    query_tail_kernel<<<1, 128, 0, stream>>>(q_emb, Wq, bq, kv, alpha_attn, out_q);
}

// Round 10
// 465.167 us; speedup vs baseline: 1.3233x; 1.0946x over previous
//
#include <hip/hip_runtime.h>

typedef unsigned int u32;

#define NS    8192
#define NQ    16384
#define DD    128
#define TOPK  32
#define RR    16
#define CAP   320
#define CAPP  321     // padded leading dim: 321 % 32 != 0 -> banks rotate per row
#define TAU   0.17f

// ---------- prep: numpy-exact norms + normalized transpose x_t[k][j] -------
// (bit-identical to the passing R6/R7 version — decision path depends on it)
__global__ __launch_bounds__(256) void prep_kernel(const float* __restrict__ s_emb,
                                                   float* __restrict__ x_t) {
    __shared__ float tile[64][129];
    __shared__ float nrm[64];
    const int row0 = blockIdx.x * 64;
    const int tid = threadIdx.x;
    for (int it = 0; it < 32; ++it) {
        int idx = it * 256 + tid;
        int rr = idx >> 7, cc = idx & 127;
        tile[rr][cc] = s_emb[(size_t)(row0 + rr) * DD + cc];
    }
    __syncthreads();
    if (tid < 64) {
        float r8[8];
#pragma unroll
        for (int c = 0; c < 8; ++c) { float v = tile[tid][c]; r8[c] = __fmul_rn(v, v); }
        for (int m = 1; m < 16; ++m) {
#pragma unroll
            for (int c = 0; c < 8; ++c) {
                float v = tile[tid][8 * m + c];
                r8[c] = __fadd_rn(r8[c], __fmul_rn(v, v));
            }
        }
        float res = __fadd_rn(
            __fadd_rn(__fadd_rn(r8[0], r8[1]), __fadd_rn(r8[2], r8[3])),
            __fadd_rn(__fadd_rn(r8[4], r8[5]), __fadd_rn(r8[6], r8[7])));
        nrm[tid] = __fsqrt_rn(res);
    }
    __syncthreads();
    const int lane = tid & 63, w = tid >> 6;
    for (int m = 0; m < 32; ++m) {
        int k = w * 32 + m;
        x_t[(size_t)k * NS + row0 + lane] = __fdiv_rn(tile[lane][k], nrm[lane]);
    }
}

// ---------- proto partial sums: 64 blocks x 128 rows ------------------------
__global__ __launch_bounds__(256) void proto_part_kernel(const float* __restrict__ s_emb,
                                                         double* __restrict__ part) {
    __shared__ double ps[256];
    const int b = blockIdx.x;              // 0..63 ; h = b>>5: 0=first half(neg),1=second(pos)
    const int h = b >> 5, seg = b & 31;
    const int tid = threadIdx.x;
    const int sub = tid >> 7, d = tid & 127;
    const size_t row0 = (size_t)h * 4096 + (size_t)seg * 128 + (size_t)sub * 64;
    double acc = 0.0;
    for (int r = 0; r < 64; ++r)
        acc += (double)s_emb[(row0 + r) * DD + d];
    ps[tid] = acc;
    __syncthreads();
    if (sub == 0) part[(size_t)b * DD + d] = ps[d] + ps[128 + d];
}

// ---------- combine partials -> prototypes -> K,V (kv = 512 floats) --------
__global__ __launch_bounds__(256) void kv_kernel(
    const double* __restrict__ part,
    const float* __restrict__ Wk, const float* __restrict__ bk,
    const float* __restrict__ Wv, const float* __restrict__ bv,
    float* __restrict__ kv) {
    __shared__ double prd[2][DD];
    const int tid = threadIdx.x;
    const int j = tid >> 7, d = tid & 127;   // j: 0=pos(second half), 1=neg(first half)
    {
        const int h = (j == 0) ? 1 : 0;
        double s = 0.0;
        for (int b = 0; b < 32; ++b) s += part[(size_t)(h * 32 + b) * DD + d];
        prd[j][d] = s * (1.0 / 4096.0);
    }
    __syncthreads();
    double ka = (double)bk[d], va = (double)bv[d];
    for (int e = 0; e < DD; ++e) {
        double p = prd[j][e];
        ka += p * (double)Wk[d * DD + e];
        va += p * (double)Wv[d * DD + e];
    }
    kv[j * DD + d]          = (float)ka;
    kv[2 * DD + j * DD + d] = (float)va;
}

// ---------- sim + top-32 + aggregate; exact chain, ties -> HIGHER index ----
__global__ __launch_bounds__(256, 3) void sim_topk_kernel(
    const float* __restrict__ s_emb, const float* __restrict__ x_t,
    const float* __restrict__ alpha_p, float* __restrict__ out_s) {
    __shared__ float ti[DD][RR];          // i-tile, k-major (8 KB), rows 64B
    __shared__ float candv[RR][CAPP];     // padded: bank-rotated rows
    __shared__ int   candj[RR][CAPP];
    __shared__ int   cnt[RR];
    __shared__ int   winners[RR][TOPK];

    const int i0 = blockIdx.x * RR;
    const int tid = threadIdx.x;
    if (tid < RR) cnt[tid] = 0;
    for (int u = tid; u < DD * RR; u += 256) {
        int k = u >> 4, r = u & 15;
        ti[k][r] = x_t[(size_t)k * NS + i0 + r];
    }
    __syncthreads();

    // ---- sim pass: per (i,j) a single sequential FMA chain over k ascending
    // thread owns 4 CONTIGUOUS j -> one float4 global load per k
    for (int jt = 0; jt < 8; ++jt) {
        const int jb = jt * 1024 + tid * 4;   // j = jb + c, c=0..3
        float acc[RR][4];
#pragma unroll
        for (int r = 0; r < RR; ++r) {
            acc[r][0] = 0.f; acc[r][1] = 0.f; acc[r][2] = 0.f; acc[r][3] = 0.f;
        }
        for (int k = 0; k < DD; ++k) {
            float4 xj = *(const float4*)(x_t + (size_t)k * NS + jb);
            const float4* tr = (const float4*)&ti[k][0];   // wave-uniform b128 reads
#pragma unroll
            for (int rq = 0; rq < 4; ++rq) {
                float4 tv = tr[rq];
                float tvs[4] = {tv.x, tv.y, tv.z, tv.w};
#pragma unroll
                for (int rc = 0; rc < 4; ++rc) {
                    const int r = rq * 4 + rc;
                    const float w = tvs[rc];
                    acc[r][0] = fmaf(w, xj.x, acc[r][0]);
                    acc[r][1] = fmaf(w, xj.y, acc[r][1]);
                    acc[r][2] = fmaf(w, xj.z, acc[r][2]);
                    acc[r][3] = fmaf(w, xj.w, acc[r][3]);
                }
            }
        }
#pragma unroll
        for (int r = 0; r < RR; ++r) {
#pragma unroll
            for (int c = 0; c < 4; ++c) {
                if (acc[r][c] >= TAU) {
                    int p = atomicAdd(&cnt[r], 1);
                    if (p < CAP) { candv[r][p] = acc[r][c]; candj[r][p] = jb + c; }
                }
            }
        }
    }
    __syncthreads();

    // ---- top-32 per row (val desc, idx DESC on ties); shfl within 16 lanes -
    const int r = tid >> 4, t = tid & 15;
    const int n = (cnt[r] < CAP) ? cnt[r] : CAP;
    for (int it = 0; it < TOPK; ++it) {
        float bv = -3.0e38f; int bj = -1, bp = -1;
        for (int p = t; p < n; p += 16) {
            float v = candv[r][p]; int j = candj[r][p];
            if (v > bv || (v == bv && j > bj)) { bv = v; bj = j; bp = p; }
        }
#pragma unroll
        for (int m = 1; m < 16; m <<= 1) {
            float ov = __shfl_xor(bv, m, 16);
            int   oj = __shfl_xor(bj, m, 16);
            int   op = __shfl_xor(bp, m, 16);
            if (ov > bv || (ov == bv && oj > bj)) { bv = ov; bj = oj; bp = op; }
        }
        if (t == 0) winners[r][it] = ((u32)bj < NS) ? bj : 0;
        if (bp >= 0 && (bp & 15) == t) candv[r][bp] = -3.0e38f;  // owner removes
    }

    // ---- sort winners ascending (same wave that wrote them) ----------------
    if (t == 0) {
        for (int a = 1; a < TOPK; ++a) {
            int key = winners[r][a]; int b = a - 1;
            while (b >= 0 && winners[r][b] > key) { winners[r][b + 1] = winners[r][b]; --b; }
            winners[r][b + 1] = key;
        }
    }
    __syncthreads();

    // ---- aggregate + epilogue (unchanged bitwise) --------------------------
    const float alpha = alpha_p[0];
    const int d = tid & 127;
    for (int rp = 0; rp < 8; ++rp) {
        const int rw = rp * 2 + (tid >> 7);
        float a = 0.0f;
        for (int w = 0; w < TOPK; ++w)
            a = __fadd_rn(a, s_emb[(size_t)winners[rw][w] * DD + d]);
        float base = s_emb[(size_t)(i0 + rw) * DD + d];
        out_s[(size_t)(i0 + rw) * DD + d] = __fadd_rn(base, __fmul_rn(alpha, a));
    }
}

// ---------- queries: LDS-tiled GEMM (64 rows/block) + 2-way attention ------
__global__ __launch_bounds__(256) void query_kernel(
    const float* __restrict__ q_emb, const float* __restrict__ Wq,
    const float* __restrict__ bq, const float* __restrict__ kv,
    const float* __restrict__ alpha_p, float* __restrict__ out_q) {
    __shared__ float wqT[DD][132];    // [e][d]
    __shared__ float qtT[DD][68];     // [e][i]
    __shared__ float qo[64][129];     // Q outputs [i][d]
    __shared__ float a0s[64], a1s[64];
    const int row0 = blockIdx.x * 64;
    const int tid = threadIdx.x;

    for (int u = tid; u < DD * DD; u += 256) {
        int dd = u >> 7, ee = u & 127;
        wqT[ee][dd] = Wq[u];
    }
    for (int u = tid; u < 64 * DD; u += 256) {
        int ii = u >> 7, ee = u & 127;
        qtT[ee][ii] = q_emb[(size_t)row0 * DD + u];
    }
    __syncthreads();

    const int d0 = (tid & 31) * 4, i0 = (tid >> 5) * 8;
    float acc[8][4];
    {
        float b0 = bq[d0], b1 = bq[d0 + 1], b2 = bq[d0 + 2], b3 = bq[d0 + 3];
#pragma unroll
        for (int ii = 0; ii < 8; ++ii) {
            acc[ii][0] = b0; acc[ii][1] = b1; acc[ii][2] = b2; acc[ii][3] = b3;
        }
    }
    for (int e = 0; e < DD; ++e) {
        float4 wv = *(const float4*)&wqT[e][d0];
        float4 qa = *(const float4*)&qtT[e][i0];
        float4 qb = *(const float4*)&qtT[e][i0 + 4];
        float qs[8] = {qa.x, qa.y, qa.z, qa.w, qb.x, qb.y, qb.z, qb.w};
#pragma unroll
        for (int ii = 0; ii < 8; ++ii) {
            acc[ii][0] = fmaf(qs[ii], wv.x, acc[ii][0]);
            acc[ii][1] = fmaf(qs[ii], wv.y, acc[ii][1]);
            acc[ii][2] = fmaf(qs[ii], wv.z, acc[ii][2]);
            acc[ii][3] = fmaf(qs[ii], wv.w, acc[ii][3]);
        }
    }
#pragma unroll
    for (int ii = 0; ii < 8; ++ii) {
        qo[i0 + ii][d0 + 0] = acc[ii][0];
        qo[i0 + ii][d0 + 1] = acc[ii][1];
        qo[i0 + ii][d0 + 2] = acc[ii][2];
        qo[i0 + ii][d0 + 3] = acc[ii][3];
    }
    __syncthreads();
    if (tid < 64) {
        float l0 = 0.f, l1 = 0.f;
        for (int e = 0; e < DD; ++e) {
            float q = qo[tid][e];
            l0 = fmaf(q, kv[e], l0);
            l1 = fmaf(q, kv[DD + e], l1);
        }
        const float inv_scale = 0.088388347648318447f;   // 1/sqrt(128)
        l0 *= inv_scale; l1 *= inv_scale;
        float m = fmaxf(l0, l1);
        float e0 = expf(l0 - m), e1 = expf(l1 - m);
        float inv = 1.0f / (e0 + e1);
        a0s[tid] = e0 * inv; a1s[tid] = e1 * inv;
    }
    __syncthreads();
    const float alpha = alpha_p[0];
    for (int w = 0; w < 32; ++w) {
        int idx = w * 256 + tid;
        int ii = idx >> 7, dd = idx & 127;
        int gi = row0 + ii;
        if (gi < NQ - 4) {
            float ctx = a0s[ii] * kv[2 * DD + dd] + a1s[ii] * kv[3 * DD + dd];
            out_q[(size_t)gi * DD + dd] =
                __fadd_rn(q_emb[(size_t)gi * DD + dd], __fmul_rn(alpha, ctx));
        }
    }
}

// ---------- last 4 query rows (their output slots host the kv scratch) -----
__global__ __launch_bounds__(128) void query_tail_kernel(
    const float* __restrict__ q_emb, const float* __restrict__ Wq,
    const float* __restrict__ bq, const float* __restrict__ kvg,
    const float* __restrict__ alpha_p, float* __restrict__ out_q) {
    __shared__ float kvl[512];
    __shared__ float qv[DD];
    __shared__ float r0[DD], r1[DD];
    const int d = threadIdx.x;
#pragma unroll
    for (int c = 0; c < 4; ++c) kvl[c * DD + d] = kvg[c * DD + d];
    __syncthreads();

    for (int rr = 0; rr < 4; ++rr) {
        const int i = NQ - 4 + rr;
        qv[d] = q_emb[(size_t)i * DD + d];
        __syncthreads();
        float acc = bq[d];
        const float4* wr = (const float4*)(Wq + (size_t)d * DD);
#pragma unroll
        for (int c = 0; c < 32; ++c) {
            float4 w = wr[c];
            const int e = c * 4;
            acc += qv[e + 0] * w.x;
            acc += qv[e + 1] * w.y;
            acc += qv[e + 2] * w.z;
            acc += qv[e + 3] * w.w;
        }
        r0[d] = acc * kvl[d];
        r1[d] = acc * kvl[DD + d];
        __syncthreads();
#pragma unroll
        for (int s = 64; s > 0; s >>= 1) {
            if (d < s) { r0[d] += r0[d + s]; r1[d] += r1[d + s]; }
            __syncthreads();
        }
        const float inv_scale = 0.088388347648318447f;
        float l0 = r0[0] * inv_scale;
        float l1 = r1[0] * inv_scale;
        float m = fmaxf(l0, l1);
        float e0 = expf(l0 - m), e1 = expf(l1 - m);
        float inv = 1.0f / (e0 + e1);
        float a0 = e0 * inv, a1 = e1 * inv;
        float ctx = a0 * kvl[2 * DD + d] + a1 * kvl[3 * DD + d];
        float alpha = alpha_p[0];
        float res = __fadd_rn(qv[d], __fmul_rn(alpha, ctx));
        __syncthreads();
        out_q[(size_t)i * DD + d] = res;
        __syncthreads();
    }
}

extern "C" void kernel_launch(void* const* d_in, const int* in_sizes, int n_in,
                              void* d_out, int out_size, void* d_ws, size_t ws_size,
                              hipStream_t stream) {
    (void)in_sizes; (void)n_in; (void)d_ws; (void)ws_size; (void)out_size;
    const float* s_emb = (const float*)d_in[0];
    const float* q_emb = (const float*)d_in[1];
    const float* Wq = (const float*)d_in[2];
    const float* bq = (const float*)d_in[3];
    const float* Wk = (const float*)d_in[4];
    const float* bk = (const float*)d_in[5];
    const float* Wv = (const float*)d_in[6];
    const float* bv = (const float*)d_in[7];
    const float* alpha_msg  = (const float*)d_in[8];
    const float* alpha_attn = (const float*)d_in[9];
    float* out = (float*)d_out;

    float*  out_q = out + (size_t)NS * DD;                  // query outputs
    float*  x_t   = out_q;                                  // 4 MB scratch (out_q rows 0..8191)
    double* part  = (double*)(out_q + (size_t)NS * DD);     // 64 KB (out_q rows 8192..8319)
    float*  kv    = out + (size_t)(NS + NQ) * DD - 512;     // last 4 rows of out_q

    prep_kernel<<<NS / 64, 256, 0, stream>>>(s_emb, x_t);
    proto_part_kernel<<<64, 256, 0, stream>>>(s_emb, part);
    kv_kernel<<<1, 256, 0, stream>>>(part, Wk, bk, Wv, bv, kv);
    sim_topk_kernel<<<NS / RR, 256, 0, stream>>>(s_emb, x_t, alpha_msg, out);
    query_kernel<<<NQ / 64, 256, 0, stream>>>(q_emb, Wq, bq, kv, alpha_attn, out_q);
    query_tail_kernel<<<1, 128, 0, stream>>>(q_emb, Wq, bq, kv, alpha_attn, out_q);
}